// Round 12
// baseline (138.710 us; speedup 1.0000x reference)
//
#include <hip/hip_runtime.h>

#define IN_F 1024
#define OUT_F 1024
#define NNZ 16384

typedef _Float16 f16;
typedef _Float16 f16x4 __attribute__((ext_vector_type(4)));
typedef _Float16 f16x8 __attribute__((ext_vector_type(8)));
typedef float f32x4 __attribute__((ext_vector_type(4)));
typedef float f32x16 __attribute__((ext_vector_type(16)));
typedef unsigned short ushort8 __attribute__((ext_vector_type(8)));

#define AS1 __attribute__((address_space(1)))
#define AS3 __attribute__((address_space(3)))

// ---------------------------------------------------------------------------
// Workspace: S = staged W_eff (f16, 2 MiB) @0; mode flag @2MiB; Xs @2MiB+4096.
// Staged layout (quarters, both S and Xs): quarter qidx = g2*16 + kt
// (g2 = 64-row group, kt = 64-K tile) = [64 rows][64 k] = 512 slots x 16B;
// slot u = r*8 + bb holds M[g2*64+r][kt*64 + ((bb^(r&7))<<3) .. +8].
//
// SYNC INVARIANT (r9): DMA-staged LDS is written by ALL waves; vmcnt drains
// only the issuing wave's loads -> every cross-wave read of a staged buffer
// must be preceded by VMW(n) -> s_barrier.
// ---------------------------------------------------------------------------

__global__ void detect_mode(const unsigned short* __restrict__ w, int* __restrict__ mode) {
  __shared__ float smax[256];
  __shared__ int semax[256];
  int t = threadIdx.x;
  const float* wf = (const float*)w;
  float m32 = fabsf(wf[t]);
  m32 = fmaxf(m32, fabsf(wf[t + 256]));
  int e8 = 0;
#pragma unroll
  for (int j = 0; j < 8; ++j) {
    unsigned short u = w[t * 8 + j];
    int e = (u >> 7) & 0xFF;
    e8 = e > e8 ? e : e8;
  }
  smax[t] = m32; semax[t] = e8;
  __syncthreads();
  for (int s = 128; s > 0; s >>= 1) {
    if (t < s) {
      smax[t] = fmaxf(smax[t], smax[t + s]);
      semax[t] = semax[t] > semax[t + s] ? semax[t] : semax[t + s];
    }
    __syncthreads();
  }
  if (t == 0) {
    int m;
    if (!(smax[0] > 1e-6f)) m = 2;        // native f16
    else if (semax[0] >= 140) m = 0;      // f32 (upcast from fp16)
    else m = 1;                           // bf16
    *mode = m;
  }
}

__device__ __forceinline__ float load_w(const void* base, size_t i, int mode) {
  if (mode == 0) return ((const float*)base)[i];
  if (mode == 1) {
    unsigned int u = (unsigned int)((const unsigned short*)base)[i] << 16;
    return __uint_as_float(u);
  }
  return (float)((const f16*)base)[i];
}

__global__ void prep_base(const void* __restrict__ base, f16* __restrict__ S,
                          const int* __restrict__ modep) {
  int mode = *modep;
  int id = blockIdx.x * 256 + threadIdx.x;   // slot id, 131072 total
  int u = id & 511;
  int qidx = id >> 9;                        // 256 quarters
  int kt = qidx & 15;
  int g2 = qidx >> 4;
  int r = u >> 3, bb = u & 7;
  int n = g2 * 64 + r;
  int k = kt * 64 + ((bb ^ (r & 7)) << 3);
  size_t off = (size_t)n * IN_F + k;
  f16x8 h;
  if (mode == 0) {
    const float* b = (const float*)base + off;
    float4 v0 = *reinterpret_cast<const float4*>(b);
    float4 v1 = *reinterpret_cast<const float4*>(b + 4);
    h = (f16x8){(f16)v0.x, (f16)v0.y, (f16)v0.z, (f16)v0.w,
                (f16)v1.x, (f16)v1.y, (f16)v1.z, (f16)v1.w};
  } else if (mode == 1) {
    ushort8 uv = *reinterpret_cast<const ushort8*>((const unsigned short*)base + off);
#pragma unroll
    for (int j = 0; j < 8; ++j)
      h[j] = (f16)__uint_as_float((unsigned int)uv[j] << 16);
  } else {
    h = *reinterpret_cast<const f16x8*>((const f16*)base + off);
  }
  *reinterpret_cast<f16x8*>(S + (size_t)id * 8) = h;
}

__global__ void prep_scatter(const void* __restrict__ base,
                             const void* __restrict__ vals,
                             const int* __restrict__ idx,
                             const float* __restrict__ alpha,
                             f16* __restrict__ S,
                             const int* __restrict__ modep) {
  int mode = *modep;
  int i = blockIdx.x * 256 + threadIdx.x;
  if (i >= NNZ) return;
  int id = idx[i];
  int n = id >> 10, k = id & 1023;
  float v = load_w(base, id, mode) + alpha[0] * load_w(vals, i, mode);
  int g2 = n >> 6, r = n & 63;
  int kt = k >> 6, kk = k & 63;
  int b = kk >> 3, e = kk & 7;
  int bb = b ^ (r & 7);
  size_t pos = (((size_t)(g2 * 16 + kt)) * 512 + (size_t)(r * 8 + bb)) * 8 + (size_t)e;
  S[pos] = (f16)v;
}

// conv_x v4: unit = 2 consecutive slots (same row; blocks b0, b0^1 form an
// aligned 64B pair in X) -> one 64B load + one contiguous 32B store per iter.
__global__ void __launch_bounds__(256) conv_x(const float* __restrict__ X,
                                              f16* __restrict__ Xs, int nunits) {
  int stride = gridDim.x * 256;
  for (int id = blockIdx.x * 256 + threadIdx.x; id < nunits; id += stride) {
    int u2 = id & 255;                 // 2-slot unit within quarter
    int qidx = id >> 8;
    int kt = qidx & 15;
    int g2 = qidx >> 4;
    int r = u2 >> 2;                   // row in quarter
    int bb = (u2 & 3) * 2;             // even block index
    int b0 = bb ^ (r & 7);
    int pb = b0 & ~1;                  // 64B-aligned pair base
    size_t row = (size_t)g2 * 64 + r;
    const float* p = X + row * IN_F + kt * 64 + pb * 8;
    float4 w0 = reinterpret_cast<const float4*>(p)[0];
    float4 w1 = reinterpret_cast<const float4*>(p)[1];
    float4 w2 = reinterpret_cast<const float4*>(p)[2];
    float4 w3 = reinterpret_cast<const float4*>(p)[3];
    f16x8 lo = {(f16)w0.x, (f16)w0.y, (f16)w0.z, (f16)w0.w,
                (f16)w1.x, (f16)w1.y, (f16)w1.z, (f16)w1.w};
    f16x8 hi = {(f16)w2.x, (f16)w2.y, (f16)w2.z, (f16)w2.w,
                (f16)w3.x, (f16)w3.y, (f16)w3.z, (f16)w3.w};
    f16* dst = Xs + (size_t)id * 16;
    if (b0 & 1) {                      // slot u holds the odd block
      *reinterpret_cast<f16x8*>(dst) = hi;
      *reinterpret_cast<f16x8*>(dst + 8) = lo;
    } else {
      *reinterpret_cast<f16x8*>(dst) = lo;
      *reinterpret_cast<f16x8*>(dst + 8) = hi;
    }
  }
}

#define SB0 __builtin_amdgcn_sched_barrier(0)
#define VMW(N) asm volatile("s_waitcnt vmcnt(" #N ")" ::: "memory")

// ---------------------------------------------------------------------------
// gemm7: gemm5's replay-proven 2-barrier fat-phase skeleton + 32x32x16 MFMA.
// 256x256, BK=64, 512 thr (8 waves 2Mx4N), wave tile 128x64.
// Per fat phase (k-half S_): 12 x ds_read_b128 (A 8: 4 mb x 2 ks; B 4:
// 2 nb x 2 ks) + 16 x mfma_f32_32x32x16_f16 (4 mb x 2 nb x 2 ks).
// A frag: row=lane&31, k=(lane>>5)*8+e; logical block b_ = S_*4+ks*2+(lane>>5),
// LDS addr = qbase + r_*64 + ((b_^(r_&7))<<3).
// C/D: col=lane&31, row=(reg&3)+8*(reg>>2)+4*(lane>>5)  [m74/m101].
// ---------------------------------------------------------------------------

#define ISSUE_QA(QI, KT1, PB)                                                  \
    __builtin_amdgcn_global_load_lds(                                          \
        (const AS1 void*)(Xs + ((size_t)((mt * 4 + (QI)) * 16 + (KT1))) * 4096 + t * 8), \
        (AS3 void*)(&sA[((PB) * 4 + (QI)) * 4096 + t * 8]), 16, 0, 0)

#define ISSUE_QB(QI, KT1, PB)                                                  \
    __builtin_amdgcn_global_load_lds(                                          \
        (const AS1 void*)(Swz + ((size_t)((nt * 4 + (QI)) * 16 + (KT1))) * 4096 + t * 8), \
        (AS3 void*)(&sB[((PB) * 4 + (QI)) * 4096 + t * 8]), 16, 0, 0)

#define DSREAD32(P, S_) do {                                                   \
    _Pragma("unroll")                                                          \
    for (int mb_ = 0; mb_ < 4; ++mb_) {                                        \
      int qa_ = ((P) * 4 + wm * 2 + (mb_ >> 1)) * 4096;                        \
      int r_ = (mb_ & 1) * 32 + l31;                                           \
      _Pragma("unroll")                                                        \
      for (int ks_ = 0; ks_ < 2; ++ks_) {                                      \
        int b_ = (S_) * 4 + ks_ * 2 + hi5;                                     \
        afr[mb_][ks_] = *reinterpret_cast<const f16x8*>(                       \
            &sA[qa_ + r_ * 64 + ((b_ ^ (r_ & 7)) << 3)]);                      \
      }                                                                        \
    }                                                                          \
    int qb_ = ((P) * 4 + wn) * 4096;                                           \
    _Pragma("unroll")                                                          \
    for (int nb_ = 0; nb_ < 2; ++nb_) {                                        \
      int r_ = nb_ * 32 + l31;                                                 \
      _Pragma("unroll")                                                        \
      for (int ks_ = 0; ks_ < 2; ++ks_) {                                      \
        int b_ = (S_) * 4 + ks_ * 2 + hi5;                                     \
        bfr[nb_][ks_] = *reinterpret_cast<const f16x8*>(                       \
            &sB[qb_ + r_ * 64 + ((b_ ^ (r_ & 7)) << 3)]);                      \
      }                                                                        \
    }                                                                          \
  } while (0)

#define MFMA16W do {                                                           \
    asm volatile("s_waitcnt lgkmcnt(0)" ::: "memory");                         \
    SB0;                                                                       \
    __builtin_amdgcn_s_setprio(1);                                             \
    _Pragma("unroll")                                                          \
    for (int mb_ = 0; mb_ < 4; ++mb_)                                          \
      _Pragma("unroll")                                                        \
      for (int nb_ = 0; nb_ < 2; ++nb_)                                        \
        _Pragma("unroll")                                                      \
        for (int ks_ = 0; ks_ < 2; ++ks_)                                      \
          acc[mb_ * 2 + nb_] = __builtin_amdgcn_mfma_f32_32x32x16_f16(         \
              afr[mb_][ks_], bfr[nb_][ks_], acc[mb_ * 2 + nb_], 0, 0, 0);      \
    __builtin_amdgcn_s_setprio(0);                                             \
  } while (0)

#define KTILE7(P, KT, PREF) do {                                               \
    /* ---- ph0 (S=0) ---- */                                                  \
    if (PREF) { ISSUE_QA(0, (KT) + 1, (P) ^ 1); ISSUE_QA(1, (KT) + 1, (P) ^ 1);\
                ISSUE_QA(2, (KT) + 1, (P) ^ 1); ISSUE_QA(3, (KT) + 1, (P) ^ 1);\
                SB0; VMW(4); }                                                 \
    else { VMW(0); }                                                           \
    SB0;                                                                       \
    __builtin_amdgcn_s_barrier();   /* RAW gate: buffer P fully resident */    \
    SB0;                                                                       \
    DSREAD32(P, 0);                                                            \
    if (PREF) { SB0; ISSUE_QB(0, (KT) + 1, (P) ^ 1); ISSUE_QB(1, (KT) + 1, (P) ^ 1);\
                ISSUE_QB(2, (KT) + 1, (P) ^ 1); ISSUE_QB(3, (KT) + 1, (P) ^ 1); } \
    MFMA16W;                                                                   \
    /* ---- ph1 (S=1) ---- */                                                  \
    DSREAD32(P, 1);                                                            \
    MFMA16W;                                                                   \
    SB0;                                                                       \
    __builtin_amdgcn_s_barrier();   /* WAR gate: reads of P complete */        \
    SB0;                                                                       \
  } while (0)

__global__ void __launch_bounds__(512, 2) gemm7(const f16* __restrict__ Xs,
                                                const f16* __restrict__ Swz,
                                                float* __restrict__ C) {
  extern __shared__ f16 lds[];
  f16* sA = lds;            // [2buf][4 quarters][4096]
  f16* sB = lds + 32768;

  int bidx = blockIdx.x;
  int q = gridDim.x >> 3;
  int wg = (bidx & 7) * q + (bidx >> 3);
  int mt = wg >> 2, nt = wg & 3;

  int t = threadIdx.x;
  int lane = t & 63;
  int w = t >> 6;
  int wm = w >> 2;           // M half (128 rows) -> A quarters 2wm, 2wm+1
  int wn = w & 3;            // N quarter (64 cols) == B row-quarter
  int l31 = lane & 31;
  int hi5 = lane >> 5;

  f16x8 afr[4][2], bfr[2][2];
  f32x16 acc[8];
#pragma unroll
  for (int i = 0; i < 8; ++i)
#pragma unroll
    for (int j = 0; j < 16; ++j)
      acc[i][j] = 0.f;

  // prologue: DMA tile 0 -> buf0; full drain + barrier (r9 invariant)
  ISSUE_QA(0, 0, 0); ISSUE_QA(1, 0, 0); ISSUE_QA(2, 0, 0); ISSUE_QA(3, 0, 0);
  ISSUE_QB(0, 0, 0); ISSUE_QB(1, 0, 0); ISSUE_QB(2, 0, 0); ISSUE_QB(3, 0, 0);
  VMW(0);
  __builtin_amdgcn_s_barrier();
  SB0;

  for (int kt2 = 0; kt2 < 14; kt2 += 2) {
    KTILE7(0, kt2, true);
    KTILE7(1, kt2 + 1, true);
  }
  KTILE7(0, 14, true);
  KTILE7(1, 15, false);

  // epilogue: C/D 32x32 layout col=l31, row=(reg&3)+8*(reg>>2)+4*hi5
  float* Cw = C + (size_t)(mt * 256 + wm * 128) * OUT_F + nt * 256 + wn * 64 + l31;
#pragma unroll
  for (int i = 0; i < 8; ++i) {
    int mb = i >> 1, nb = i & 1;
#pragma unroll
    for (int r = 0; r < 16; ++r) {
      int rowin = (r & 3) + 8 * (r >> 2) + 4 * hi5;
      Cw[(size_t)(mb * 32 + rowin) * OUT_F + nb * 32] = acc[i][r];
    }
  }
}

extern "C" void kernel_launch(void* const* d_in, const int* in_sizes, int n_in,
                              void* d_out, int out_size, void* d_ws, size_t ws_size,
                              hipStream_t stream) {
  const float* X = (const float*)d_in[0];
  const void* base = d_in[1];
  const void* vals = d_in[2];
  const int* idx = (const int*)d_in[3];
  const float* alpha = (const float*)d_in[4];
  float* out = (float*)d_out;
  f16* S = (f16*)d_ws;
  int* modep = (int*)((char*)d_ws + 2 * 1024 * 1024);
  f16* Xs = (f16*)((char*)d_ws + 2 * 1024 * 1024 + 4096);

  int M = in_sizes[0] / IN_F;              // 32768
  int nunits = (M * IN_F) / 16;            // 2-slot units

  (void)hipFuncSetAttribute(reinterpret_cast<const void*>(&gemm7),
                            hipFuncAttributeMaxDynamicSharedMemorySize, 131072);

  detect_mode<<<dim3(1), dim3(256), 0, stream>>>((const unsigned short*)base, modep);
  prep_base<<<dim3(512), dim3(256), 0, stream>>>(base, S, modep);
  prep_scatter<<<dim3((NNZ + 255) / 256), dim3(256), 0, stream>>>(base, vals, idx, alpha, S, modep);
  conv_x<<<dim3(2048), dim3(256), 0, stream>>>(X, Xs, nunits);
  gemm7<<<dim3((M / 256) * 4), dim3(512), 131072, stream>>>(Xs, S, out);
}